// Round 11
// baseline (3569.244 us; speedup 1.0000x reference)
//
#include <hip/hip_runtime.h>
#include <stdint.h>

typedef unsigned int uint_t;

#define S_SEG 8192
#define CIN 128
#define COUT 256
#define LN_EPS 1e-5f
#define BM 32    // rows per block in k_main_v4
#define XLD 132  // padded LDS leading dim for x rows (floats)
#define KT 16    // k-slice per weight stage

// order-preserving f32 <-> u32 keys for atomicMax-based float max
__device__ __forceinline__ uint_t fkey(float f) {
  uint_t b = __float_as_uint(f);
  return (b & 0x80000000u) ? ~b : (b | 0x80000000u);
}
__device__ __forceinline__ float funkey(uint_t k) {
  uint_t b = (k & 0x80000000u) ? (k ^ 0x80000000u) : ~k;
  return __uint_as_float(b);
}

// K0: init encoded-max buffer to key(-inf)   [passing, verbatim]
__global__ void k_xm_init(uint_t* __restrict__ enc) {
  enc[blockIdx.x * blockDim.x + threadIdx.x] = 0x007FFFFFu;
}

// K1: segment max via atomicMax on encoded floats   [passing, verbatim]
__global__ void k_xm_scatter(const float* __restrict__ x, const int* __restrict__ batch,
                             uint_t* __restrict__ enc, int N) {
  int r0 = blockIdx.x * 32;
  int c = threadIdx.x;  // 128 threads = channels
  int rend = r0 + 32; if (rend > N) rend = N;
  int cur = batch[r0];
  float m = -INFINITY;
  for (int r = r0; r < rend; ++r) {
    int b = batch[r];
    if (b != cur) {
      atomicMax(&enc[(size_t)cur * CIN + c], fkey(m));
      cur = b;
      m = -INFINITY;
    }
    m = fmaxf(m, x[(size_t)r * CIN + c]);
  }
  atomicMax(&enc[(size_t)cur * CIN + c], fkey(m));
}

// K2: decode in place; -inf (empty segment) -> 0   [passing, verbatim]
__global__ void k_xm_decode(uint_t* __restrict__ enc, float* __restrict__ xm) {
  int i = blockIdx.x * blockDim.x + threadIdx.x;
  float f = funkey(enc[i]);
  xm[i] = (f >= -3.0e38f && f <= 3.0e38f) ? f : 0.0f;
}

// K3: xml[s][o] = gamma_b[o] - dot(xm[s,:], lambda_w[o,:])   [passing, verbatim]
__global__ void k_lambda_f32(const float* __restrict__ xm, const float* __restrict__ lw,
                             const float* __restrict__ gb, float* __restrict__ xml) {
  int s = blockIdx.x;   // 0..8191
  int o = threadIdx.x;  // 0..255
  const float* xr = xm + (size_t)s * CIN;
  const float* wr = lw + (size_t)o * CIN;
  float acc = 0.f;
  for (int c = 0; c < CIN; ++c) acc += xr[c] * wr[c];
  xml[(size_t)s * COUT + o] = gb[o] - acc;
}

// K3b: transpose gw -> gwT[k][cout] (128 KB), in the dead xm ws region.
__global__ void k_gwT(const float* __restrict__ gw, float* __restrict__ gwT) {
  int i = blockIdx.x * blockDim.x + threadIdx.x;  // 32768
  int k = i >> 8, c = i & 255;
  gwT[(size_t)k * COUT + c] = gw[(size_t)c * CIN + k];
}

// K4 v4: out = PReLU(LN(x@gwT + xml[batch]))
// 256 threads, BM=32 rows; wave ty owns rows ty*8..ty*8+7; lane owns 4
// consecutive cols c0=(tid&63)*4. Weights staged LDS 16-k at a time (staged
// once per BLOCK, not read per wave -> 4x less L2 traffic). x rows in LDS,
// wave-uniform broadcast reads. acc[8] float4 = 32 VGPR; no kc unroll so
// natural pressure ~75 VGPR -> no spill under launch_bounds(256,3).
__global__ __launch_bounds__(256, 3) void k_main_v4(
    const float* __restrict__ x, const int* __restrict__ batch,
    const float* __restrict__ gwT, const float* __restrict__ xml,
    const float* __restrict__ lnw, const float* __restrict__ lnb,
    const float* __restrict__ prelu, float* __restrict__ out, int N) {
  __shared__ float xs[BM * XLD];     // 16,896 B : x rows, all 128 k
  __shared__ float wt[KT * COUT];    // 16,384 B : weight slice [16k][256c]

  const int tid = threadIdx.x;
  const int ty = tid >> 6;        // wave id = row group
  const int tx = tid & 63;
  const int c0 = tx * 4;
  const size_t row0 = (size_t)blockIdx.x * BM;

  // stage x rows (1024 float4 chunks, 4 per thread)
#pragma unroll
  for (int i = 0; i < 4; ++i) {
    int idx = tid + i * 256;
    int r = idx >> 5, ch = idx & 31;
    size_t gr = row0 + r;
    if (gr >= (size_t)N) gr = (size_t)N - 1;  // N%32==0: never fires
    *(float4*)&xs[r * XLD + ch * 4] = *(const float4*)(x + gr * CIN + ch * 4);
  }

  float4 acc[8];
#pragma unroll
  for (int r = 0; r < 8; ++r) acc[r] = (float4){0.f, 0.f, 0.f, 0.f};

  for (int kt = 0; kt < CIN / KT; ++kt) {   // 8 weight stages of 16 k
    __syncthreads();  // xs ready (kt=0) / previous compute done reading wt
    // stage wt[16][256] from gwT rows kt*16.. (1024 float4, 4 per thread)
#pragma unroll
    for (int i = 0; i < 4; ++i) {
      int idx = tid + i * 256;
      int k = idx >> 6, c4 = (idx & 63) * 4;
      *(float4*)&wt[k * COUT + c4] =
          *(const float4*)(gwT + (size_t)(kt * KT + k) * COUT + c4);
    }
    __syncthreads();
    // compute this k-slice: 4 chunks of 4 k
    for (int kc = 0; kc < 4; ++kc) {
      float4 w0 = *(const float4*)&wt[(kc * 4 + 0) * COUT + c0];
      float4 w1 = *(const float4*)&wt[(kc * 4 + 1) * COUT + c0];
      float4 w2 = *(const float4*)&wt[(kc * 4 + 2) * COUT + c0];
      float4 w3 = *(const float4*)&wt[(kc * 4 + 3) * COUT + c0];
#pragma unroll
      for (int r = 0; r < 8; ++r) {
        float4 xv = *(const float4*)&xs[(ty * 8 + r) * XLD + kt * KT + kc * 4];
        acc[r].x += xv.x * w0.x + xv.y * w1.x + xv.z * w2.x + xv.w * w3.x;
        acc[r].y += xv.x * w0.y + xv.y * w1.y + xv.z * w2.y + xv.w * w3.y;
        acc[r].z += xv.x * w0.z + xv.y * w1.z + xv.z * w2.z + xv.w * w3.z;
        acc[r].w += xv.x * w0.w + xv.y * w1.w + xv.z * w2.w + xv.w * w3.w;
      }
    }
  }

  // epilogue: whole wave handles one row at a time -> 64-lane LN reduce
  const float4 lw4 = *(const float4*)(lnw + c0);
  const float4 lb4 = *(const float4*)(lnb + c0);
  const float asl = prelu[0];
#pragma unroll
  for (int r = 0; r < 8; ++r) {
    size_t row = row0 + (size_t)(ty * 8 + r);
    if (row >= (size_t)N) continue;         // wave-uniform
    const float* xmlr = xml + (size_t)batch[row] * COUT;
    float4 m4 = *(const float4*)(xmlr + c0);
    float4 v;
    v.x = acc[r].x + m4.x; v.y = acc[r].y + m4.y;
    v.z = acc[r].z + m4.z; v.w = acc[r].w + m4.w;
    float sum = v.x + v.y + v.z + v.w;
    float ssq = v.x * v.x + v.y * v.y + v.z * v.z + v.w * v.w;
#pragma unroll
    for (int m = 1; m < 64; m <<= 1) {      // full-wave reduce over 256 cols
      sum += __shfl_xor(sum, m);
      ssq += __shfl_xor(ssq, m);
    }
    float mu = sum * (1.f / 256.f);
    float var = ssq * (1.f / 256.f) - mu * mu;
    float rs = rsqrtf(var + LN_EPS);
    float4 o; float t;
    t = (v.x - mu) * rs * lw4.x + lb4.x; o.x = (t >= 0.f) ? t : asl * t;
    t = (v.y - mu) * rs * lw4.y + lb4.y; o.y = (t >= 0.f) ? t : asl * t;
    t = (v.z - mu) * rs * lw4.z + lb4.z; o.z = (t >= 0.f) ? t : asl * t;
    t = (v.w - mu) * rs * lw4.w + lb4.w; o.w = (t >= 0.f) ? t : asl * t;
    *(float4*)(out + row * COUT + c0) = o;
  }
}

extern "C" void kernel_launch(void* const* d_in, const int* in_sizes, int n_in,
                              void* d_out, int out_size, void* d_ws, size_t ws_size,
                              hipStream_t stream) {
  const float* x     = (const float*)d_in[0];
  const int*   batch = (const int*)d_in[1];
  const float* gw    = (const float*)d_in[2];
  const float* gb    = (const float*)d_in[3];
  const float* lw    = (const float*)d_in[4];
  const float* lnw   = (const float*)d_in[5];
  const float* lnb   = (const float*)d_in[6];
  const float* pa    = (const float*)d_in[7];
  float* out = (float*)d_out;
  const int N = in_sizes[0] / CIN;

  // ws, TOTAL 12 MB (verified): [0,4MB) enc/xm, gwT reuses it after k_lambda;
  // [4MB,12MB) xml.
  char* w8 = (char*)d_ws;
  uint_t* enc = (uint_t*)w8;
  float* xm   = (float*)w8;                  // alias of enc (in-place decode)
  float* gwT  = (float*)w8;                  // alias of xm, valid AFTER k_lambda
  float* xml  = (float*)(w8 + 4194304);

  k_xm_init<<<(S_SEG * CIN) / 256, 256, 0, stream>>>(enc);
  k_xm_scatter<<<(N + 31) / 32, CIN, 0, stream>>>(x, batch, enc, N);
  k_xm_decode<<<(S_SEG * CIN) / 256, 256, 0, stream>>>(enc, xm);
  k_lambda_f32<<<S_SEG, COUT, 0, stream>>>(xm, lw, gb, xml);
  k_gwT<<<(COUT * CIN) / 256, 256, 0, stream>>>(gw, gwT);  // xm dead now
  k_main_v4<<<(N + BM - 1) / BM, 256, 0, stream>>>(x, batch, gwT, xml, lnw, lnb, pa, out, N);
}

// Round 12
// 1400.757 us; speedup vs baseline: 2.5481x; 2.5481x over previous
//
#include <hip/hip_runtime.h>
#include <stdint.h>

typedef unsigned int uint_t;

#define S_SEG 8192
#define CIN 128
#define COUT 256
#define LN_EPS 1e-5f
#define BM 64    // rows per block in k_main_v5 (16 rows per wave)
#define XLD 132  // padded LDS leading dim for x rows (floats)

// order-preserving f32 <-> u32 keys for atomicMax-based float max
__device__ __forceinline__ uint_t fkey(float f) {
  uint_t b = __float_as_uint(f);
  return (b & 0x80000000u) ? ~b : (b | 0x80000000u);
}
__device__ __forceinline__ float funkey(uint_t k) {
  uint_t b = (k & 0x80000000u) ? (k ^ 0x80000000u) : ~k;
  return __uint_as_float(b);
}

// K0: init encoded-max buffer to key(-inf)   [passing, verbatim]
__global__ void k_xm_init(uint_t* __restrict__ enc) {
  enc[blockIdx.x * blockDim.x + threadIdx.x] = 0x007FFFFFu;
}

// K1: segment max via atomicMax on encoded floats   [passing, verbatim]
__global__ void k_xm_scatter(const float* __restrict__ x, const int* __restrict__ batch,
                             uint_t* __restrict__ enc, int N) {
  int r0 = blockIdx.x * 32;
  int c = threadIdx.x;  // 128 threads = channels
  int rend = r0 + 32; if (rend > N) rend = N;
  int cur = batch[r0];
  float m = -INFINITY;
  for (int r = r0; r < rend; ++r) {
    int b = batch[r];
    if (b != cur) {
      atomicMax(&enc[(size_t)cur * CIN + c], fkey(m));
      cur = b;
      m = -INFINITY;
    }
    m = fmaxf(m, x[(size_t)r * CIN + c]);
  }
  atomicMax(&enc[(size_t)cur * CIN + c], fkey(m));
}

// K2: decode in place; -inf (empty segment) -> 0   [passing, verbatim]
__global__ void k_xm_decode(uint_t* __restrict__ enc, float* __restrict__ xm) {
  int i = blockIdx.x * blockDim.x + threadIdx.x;
  float f = funkey(enc[i]);
  xm[i] = (f >= -3.0e38f && f <= 3.0e38f) ? f : 0.0f;
}

// K3: xml[s][o] = gamma_b[o] - dot(xm[s,:], lambda_w[o,:])   [passing, verbatim]
__global__ void k_lambda_f32(const float* __restrict__ xm, const float* __restrict__ lw,
                             const float* __restrict__ gb, float* __restrict__ xml) {
  int s = blockIdx.x;   // 0..8191
  int o = threadIdx.x;  // 0..255
  const float* xr = xm + (size_t)s * CIN;
  const float* wr = lw + (size_t)o * CIN;
  float acc = 0.f;
  for (int c = 0; c < CIN; ++c) acc += xr[c] * wr[c];
  xml[(size_t)s * COUT + o] = gb[o] - acc;
}

// K3b: transpose gw -> gwT[k][cout] (128 KB), in the dead xm ws region.
__global__ void k_gwT(const float* __restrict__ gw, float* __restrict__ gwT) {
  int i = blockIdx.x * blockDim.x + threadIdx.x;  // 32768
  int k = i >> 8, c = i & 255;
  gwT[(size_t)k * COUT + c] = gw[(size_t)c * CIN + k];
}

// K4 v5: out = PReLU(LN(x@gwT + xml[batch]))
// 256 threads, BM=64; wave ty owns rows ty*16..ty*16+15; lane owns 4
// consecutive cols c0=(tid&63)*4. Weights read per-wave from L2-hot gwT
// (v3 style -- the LDS-weight variant regressed). acc[16]x4 = 64 VGPR;
// launch_bounds(256,2) -> 256-VGPR cap: spill-proof by construction.
// 16 rows/wave halves gwT L2 sweeps vs v3 (8 GB aggregate).
__global__ __launch_bounds__(256, 2) void k_main_v5(
    const float* __restrict__ x, const int* __restrict__ batch,
    const float* __restrict__ gwT, const float* __restrict__ xml,
    const float* __restrict__ lnw, const float* __restrict__ lnb,
    const float* __restrict__ prelu, float* __restrict__ out, int N) {
  __shared__ float xs[BM * XLD];  // 33,792 B : x rows, all 128 k

  const int tid = threadIdx.x;
  const int ty = tid >> 6;        // wave id = 16-row group
  const int tx = tid & 63;
  const int c0 = tx * 4;
  const size_t row0 = (size_t)blockIdx.x * BM;

  // stage x rows: 64 rows x 32 float4 chunks = 2048, 8 per thread
#pragma unroll
  for (int i = 0; i < 8; ++i) {
    int idx = tid + i * 256;
    int r = idx >> 5, ch = idx & 31;
    size_t gr = row0 + r;
    if (gr >= (size_t)N) gr = (size_t)N - 1;  // N%64==0: never fires
    *(float4*)&xs[r * XLD + ch * 4] = *(const float4*)(x + gr * CIN + ch * 4);
  }
  __syncthreads();

  float4 acc[16];
#pragma unroll
  for (int r = 0; r < 16; ++r) acc[r] = (float4){0.f, 0.f, 0.f, 0.f};

  for (int kc = 0; kc < 32; ++kc) {  // k in chunks of 4 (no unroll pragma)
    const float* gk = gwT + (size_t)(kc * 4) * COUT + c0;
    float4 w0 = *(const float4*)(gk);
    float4 w1 = *(const float4*)(gk + COUT);
    float4 w2 = *(const float4*)(gk + 2 * COUT);
    float4 w3 = *(const float4*)(gk + 3 * COUT);
#pragma unroll
    for (int r = 0; r < 16; ++r) {
      float4 xv = *(const float4*)&xs[(ty * 16 + r) * XLD + kc * 4];  // broadcast
      acc[r].x += xv.x * w0.x + xv.y * w1.x + xv.z * w2.x + xv.w * w3.x;
      acc[r].y += xv.x * w0.y + xv.y * w1.y + xv.z * w2.y + xv.w * w3.y;
      acc[r].z += xv.x * w0.z + xv.y * w1.z + xv.z * w2.z + xv.w * w3.z;
      acc[r].w += xv.x * w0.w + xv.y * w1.w + xv.z * w2.w + xv.w * w3.w;
    }
  }

  // epilogue: whole wave handles one row at a time -> 64-lane LN reduce
  const float4 lw4 = *(const float4*)(lnw + c0);
  const float4 lb4 = *(const float4*)(lnb + c0);
  const float asl = prelu[0];
#pragma unroll
  for (int r = 0; r < 16; ++r) {
    size_t row = row0 + (size_t)(ty * 16 + r);
    if (row >= (size_t)N) continue;         // wave-uniform
    const float* xmlr = xml + (size_t)batch[row] * COUT;
    float4 m4 = *(const float4*)(xmlr + c0);
    float4 v;
    v.x = acc[r].x + m4.x; v.y = acc[r].y + m4.y;
    v.z = acc[r].z + m4.z; v.w = acc[r].w + m4.w;
    float sum = v.x + v.y + v.z + v.w;
    float ssq = v.x * v.x + v.y * v.y + v.z * v.z + v.w * v.w;
#pragma unroll
    for (int m = 1; m < 64; m <<= 1) {      // full-wave reduce over 256 cols
      sum += __shfl_xor(sum, m);
      ssq += __shfl_xor(ssq, m);
    }
    float mu = sum * (1.f / 256.f);
    float var = ssq * (1.f / 256.f) - mu * mu;
    float rs = rsqrtf(var + LN_EPS);
    float4 o; float t;
    t = (v.x - mu) * rs * lw4.x + lb4.x; o.x = (t >= 0.f) ? t : asl * t;
    t = (v.y - mu) * rs * lw4.y + lb4.y; o.y = (t >= 0.f) ? t : asl * t;
    t = (v.z - mu) * rs * lw4.z + lb4.z; o.z = (t >= 0.f) ? t : asl * t;
    t = (v.w - mu) * rs * lw4.w + lb4.w; o.w = (t >= 0.f) ? t : asl * t;
    *(float4*)(out + row * COUT + c0) = o;
  }
}

extern "C" void kernel_launch(void* const* d_in, const int* in_sizes, int n_in,
                              void* d_out, int out_size, void* d_ws, size_t ws_size,
                              hipStream_t stream) {
  const float* x     = (const float*)d_in[0];
  const int*   batch = (const int*)d_in[1];
  const float* gw    = (const float*)d_in[2];
  const float* gb    = (const float*)d_in[3];
  const float* lw    = (const float*)d_in[4];
  const float* lnw   = (const float*)d_in[5];
  const float* lnb   = (const float*)d_in[6];
  const float* pa    = (const float*)d_in[7];
  float* out = (float*)d_out;
  const int N = in_sizes[0] / CIN;

  // ws, TOTAL 12 MB (verified): [0,4MB) enc/xm, gwT reuses it after k_lambda;
  // [4MB,12MB) xml.
  char* w8 = (char*)d_ws;
  uint_t* enc = (uint_t*)w8;
  float* xm   = (float*)w8;                  // alias of enc (in-place decode)
  float* gwT  = (float*)w8;                  // alias of xm, valid AFTER k_lambda
  float* xml  = (float*)(w8 + 4194304);

  k_xm_init<<<(S_SEG * CIN) / 256, 256, 0, stream>>>(enc);
  k_xm_scatter<<<(N + 31) / 32, CIN, 0, stream>>>(x, batch, enc, N);
  k_xm_decode<<<(S_SEG * CIN) / 256, 256, 0, stream>>>(enc, xm);
  k_lambda_f32<<<S_SEG, COUT, 0, stream>>>(xm, lw, gb, xml);
  k_gwT<<<(COUT * CIN) / 256, 256, 0, stream>>>(gw, gwT);  // xm dead now
  k_main_v5<<<(N + BM - 1) / BM, 256, 0, stream>>>(x, batch, gwT, xml, lnw, lnb, pa, out, N);
}

// Round 14
// 1367.920 us; speedup vs baseline: 2.6092x; 1.0240x over previous
//
#include <hip/hip_runtime.h>
#include <stdint.h>

typedef unsigned int uint_t;

#define S_SEG 8192
#define CIN 128
#define COUT 256
#define LN_EPS 1e-5f
#define BM 64    // rows per block in k_main_v6 (16 rows per wave)
#define XLD 132  // padded LDS leading dim for x rows (floats)

// order-preserving f32 <-> u32 keys for atomicMax-based float max
__device__ __forceinline__ uint_t fkey(float f) {
  uint_t b = __float_as_uint(f);
  return (b & 0x80000000u) ? ~b : (b | 0x80000000u);
}
__device__ __forceinline__ float funkey(uint_t k) {
  uint_t b = (k & 0x80000000u) ? (k ^ 0x80000000u) : ~k;
  return __uint_as_float(b);
}

// K0: init encoded-max buffer to key(-inf)   [passing, verbatim]
__global__ void k_xm_init(uint_t* __restrict__ enc) {
  enc[blockIdx.x * blockDim.x + threadIdx.x] = 0x007FFFFFu;
}

// K1: segment max via atomicMax on encoded floats   [passing, verbatim]
__global__ void k_xm_scatter(const float* __restrict__ x, const int* __restrict__ batch,
                             uint_t* __restrict__ enc, int N) {
  int r0 = blockIdx.x * 32;
  int c = threadIdx.x;  // 128 threads = channels
  int rend = r0 + 32; if (rend > N) rend = N;
  int cur = batch[r0];
  float m = -INFINITY;
  for (int r = r0; r < rend; ++r) {
    int b = batch[r];
    if (b != cur) {
      atomicMax(&enc[(size_t)cur * CIN + c], fkey(m));
      cur = b;
      m = -INFINITY;
    }
    m = fmaxf(m, x[(size_t)r * CIN + c]);
  }
  atomicMax(&enc[(size_t)cur * CIN + c], fkey(m));
}

// K2: decode in place; -inf (empty segment) -> 0   [passing, verbatim]
__global__ void k_xm_decode(uint_t* __restrict__ enc, float* __restrict__ xm) {
  int i = blockIdx.x * blockDim.x + threadIdx.x;
  float f = funkey(enc[i]);
  xm[i] = (f >= -3.0e38f && f <= 3.0e38f) ? f : 0.0f;
}

// K3: xml[s][o] = gamma_b[o] - dot(xm[s,:], lambda_w[o,:])   [passing, verbatim]
__global__ void k_lambda_f32(const float* __restrict__ xm, const float* __restrict__ lw,
                             const float* __restrict__ gb, float* __restrict__ xml) {
  int s = blockIdx.x;   // 0..8191
  int o = threadIdx.x;  // 0..255
  const float* xr = xm + (size_t)s * CIN;
  const float* wr = lw + (size_t)o * CIN;
  float acc = 0.f;
  for (int c = 0; c < CIN; ++c) acc += xr[c] * wr[c];
  xml[(size_t)s * COUT + o] = gb[o] - acc;
}

// K3b: transpose gw -> gwT[k][cout] (128 KB), in the dead xm ws region.
__global__ void k_gwT(const float* __restrict__ gw, float* __restrict__ gwT) {
  int i = blockIdx.x * blockDim.x + threadIdx.x;  // 32768
  int k = i >> 8, c = i & 255;
  gwT[(size_t)k * COUT + c] = gw[(size_t)c * CIN + k];
}

// K4 v6: out = PReLU(LN(x@gwT + xml[batch]))
// v5 structure + explicit double-buffered weight prefetch: load kc+1's
// four w-float4 (registers) BEFORE the FMA burst for kc -> L2 latency
// (~200cyc) hidden under the 512-cycle FMA block. VGPR ~140 << 256 cap
// (launch_bounds(256,2)) -> spill-proof (R11/R12 lesson).
__global__ __launch_bounds__(256, 2) void k_main_v6(
    const float* __restrict__ x, const int* __restrict__ batch,
    const float* __restrict__ gwT, const float* __restrict__ xml,
    const float* __restrict__ lnw, const float* __restrict__ lnb,
    const float* __restrict__ prelu, float* __restrict__ out, int N) {
  __shared__ float xs[BM * XLD];  // 33,792 B : x rows, all 128 k

  const int tid = threadIdx.x;
  const int ty = tid >> 6;        // wave id = 16-row group
  const int tx = tid & 63;
  const int c0 = tx * 4;
  const size_t row0 = (size_t)blockIdx.x * BM;

  // stage x rows: 64 rows x 32 float4 chunks = 2048, 8 per thread
#pragma unroll
  for (int i = 0; i < 8; ++i) {
    int idx = tid + i * 256;
    int r = idx >> 5, ch = idx & 31;
    size_t gr = row0 + r;
    if (gr >= (size_t)N) gr = (size_t)N - 1;  // N%64==0: never fires
    *(float4*)&xs[r * XLD + ch * 4] = *(const float4*)(x + gr * CIN + ch * 4);
  }
  __syncthreads();

  float4 acc[16];
#pragma unroll
  for (int r = 0; r < 16; ++r) acc[r] = (float4){0.f, 0.f, 0.f, 0.f};

  // double-buffered weight prefetch over 32 k-chunks of 4
  const float* gk0 = gwT + c0;
  float4 w0 = *(const float4*)(gk0);
  float4 w1 = *(const float4*)(gk0 + COUT);
  float4 w2 = *(const float4*)(gk0 + 2 * COUT);
  float4 w3 = *(const float4*)(gk0 + 3 * COUT);
  for (int kc = 0; kc < 32; ++kc) {
    // prefetch kc+1 (clamped address; values unused on last iter)
    int kn = (kc < 31) ? (kc + 1) : 31;
    const float* gk = gwT + (size_t)(kn * 4) * COUT + c0;
    float4 n0 = *(const float4*)(gk);
    float4 n1 = *(const float4*)(gk + COUT);
    float4 n2 = *(const float4*)(gk + 2 * COUT);
    float4 n3 = *(const float4*)(gk + 3 * COUT);
#pragma unroll
    for (int r = 0; r < 16; ++r) {
      float4 xv = *(const float4*)&xs[(ty * 16 + r) * XLD + kc * 4];  // broadcast
      acc[r].x += xv.x * w0.x + xv.y * w1.x + xv.z * w2.x + xv.w * w3.x;
      acc[r].y += xv.x * w0.y + xv.y * w1.y + xv.z * w2.y + xv.w * w3.y;
      acc[r].z += xv.x * w0.z + xv.y * w1.z + xv.z * w2.z + xv.w * w3.z;
      acc[r].w += xv.x * w0.w + xv.y * w1.w + xv.z * w2.w + xv.w * w3.w;
    }
    w0 = n0; w1 = n1; w2 = n2; w3 = n3;
  }

  // epilogue: whole wave handles one row at a time -> 64-lane LN reduce
  const float4 lw4 = *(const float4*)(lnw + c0);
  const float4 lb4 = *(const float4*)(lnb + c0);
  const float asl = prelu[0];
#pragma unroll
  for (int r = 0; r < 16; ++r) {
    size_t row = row0 + (size_t)(ty * 16 + r);
    if (row >= (size_t)N) continue;         // wave-uniform
    const float* xmlr = xml + (size_t)batch[row] * COUT;
    float4 m4 = *(const float4*)(xmlr + c0);
    float4 v;
    v.x = acc[r].x + m4.x; v.y = acc[r].y + m4.y;
    v.z = acc[r].z + m4.z; v.w = acc[r].w + m4.w;
    float sum = v.x + v.y + v.z + v.w;
    float ssq = v.x * v.x + v.y * v.y + v.z * v.z + v.w * v.w;
#pragma unroll
    for (int m = 1; m < 64; m <<= 1) {      // full-wave reduce over 256 cols
      sum += __shfl_xor(sum, m);
      ssq += __shfl_xor(ssq, m);
    }
    float mu = sum * (1.f / 256.f);
    float var = ssq * (1.f / 256.f) - mu * mu;
    float rs = rsqrtf(var + LN_EPS);
    float4 o; float t;
    t = (v.x - mu) * rs * lw4.x + lb4.x; o.x = (t >= 0.f) ? t : asl * t;
    t = (v.y - mu) * rs * lw4.y + lb4.y; o.y = (t >= 0.f) ? t : asl * t;
    t = (v.z - mu) * rs * lw4.z + lb4.z; o.z = (t >= 0.f) ? t : asl * t;
    t = (v.w - mu) * rs * lw4.w + lb4.w; o.w = (t >= 0.f) ? t : asl * t;
    *(float4*)(out + row * COUT + c0) = o;
  }
}

extern "C" void kernel_launch(void* const* d_in, const int* in_sizes, int n_in,
                              void* d_out, int out_size, void* d_ws, size_t ws_size,
                              hipStream_t stream) {
  const float* x     = (const float*)d_in[0];
  const int*   batch = (const int*)d_in[1];
  const float* gw    = (const float*)d_in[2];
  const float* gb    = (const float*)d_in[3];
  const float* lw    = (const float*)d_in[4];
  const float* lnw   = (const float*)d_in[5];
  const float* lnb   = (const float*)d_in[6];
  const float* pa    = (const float*)d_in[7];
  float* out = (float*)d_out;
  const int N = in_sizes[0] / CIN;

  // ws, TOTAL 12 MB (verified): [0,4MB) enc/xm, gwT reuses it after k_lambda;
  // [4MB,12MB) xml.
  char* w8 = (char*)d_ws;
  uint_t* enc = (uint_t*)w8;
  float* xm   = (float*)w8;                  // alias of enc (in-place decode)
  float* gwT  = (float*)w8;                  // alias of xm, valid AFTER k_lambda
  float* xml  = (float*)(w8 + 4194304);

  k_xm_init<<<(S_SEG * CIN) / 256, 256, 0, stream>>>(enc);
  k_xm_scatter<<<(N + 31) / 32, CIN, 0, stream>>>(x, batch, enc, N);
  k_xm_decode<<<(S_SEG * CIN) / 256, 256, 0, stream>>>(enc, xm);
  k_lambda_f32<<<S_SEG, COUT, 0, stream>>>(xm, lw, gb, xml);
  k_gwT<<<(COUT * CIN) / 256, 256, 0, stream>>>(gw, gwT);  // xm dead now
  k_main_v6<<<(N + BM - 1) / BM, 256, 0, stream>>>(x, batch, gwT, xml, lnw, lnb, pa, out, N);
}

// Round 15
// 1250.980 us; speedup vs baseline: 2.8532x; 1.0935x over previous
//
#include <hip/hip_runtime.h>
#include <stdint.h>

typedef unsigned int uint_t;

#define S_SEG 8192
#define CIN 128
#define COUT 256
#define LN_EPS 1e-5f
#define BM 64    // rows per block in k_main_v7 (16 rows per wave)
#define XLD 132  // padded LDS leading dim for x rows (floats)

// order-preserving f32 <-> u32 keys for atomicMax-based float max
__device__ __forceinline__ uint_t fkey(float f) {
  uint_t b = __float_as_uint(f);
  return (b & 0x80000000u) ? ~b : (b | 0x80000000u);
}
__device__ __forceinline__ float funkey(uint_t k) {
  uint_t b = (k & 0x80000000u) ? (k ^ 0x80000000u) : ~k;
  return __uint_as_float(b);
}

// K0: init encoded-max buffer to key(-inf)   [passing, verbatim]
__global__ void k_xm_init(uint_t* __restrict__ enc) {
  enc[blockIdx.x * blockDim.x + threadIdx.x] = 0x007FFFFFu;
}

// K1: segment max via atomicMax on encoded floats   [passing, verbatim]
__global__ void k_xm_scatter(const float* __restrict__ x, const int* __restrict__ batch,
                             uint_t* __restrict__ enc, int N) {
  int r0 = blockIdx.x * 32;
  int c = threadIdx.x;  // 128 threads = channels
  int rend = r0 + 32; if (rend > N) rend = N;
  int cur = batch[r0];
  float m = -INFINITY;
  for (int r = r0; r < rend; ++r) {
    int b = batch[r];
    if (b != cur) {
      atomicMax(&enc[(size_t)cur * CIN + c], fkey(m));
      cur = b;
      m = -INFINITY;
    }
    m = fmaxf(m, x[(size_t)r * CIN + c]);
  }
  atomicMax(&enc[(size_t)cur * CIN + c], fkey(m));
}

// K2: decode in place; -inf (empty segment) -> 0   [passing, verbatim]
__global__ void k_xm_decode(uint_t* __restrict__ enc, float* __restrict__ xm) {
  int i = blockIdx.x * blockDim.x + threadIdx.x;
  float f = funkey(enc[i]);
  xm[i] = (f >= -3.0e38f && f <= 3.0e38f) ? f : 0.0f;
}

// K3: xml[s][o] = gamma_b[o] - dot(xm[s,:], lambda_w[o,:])   [passing, verbatim]
__global__ void k_lambda_f32(const float* __restrict__ xm, const float* __restrict__ lw,
                             const float* __restrict__ gb, float* __restrict__ xml) {
  int s = blockIdx.x;   // 0..8191
  int o = threadIdx.x;  // 0..255
  const float* xr = xm + (size_t)s * CIN;
  const float* wr = lw + (size_t)o * CIN;
  float acc = 0.f;
  for (int c = 0; c < CIN; ++c) acc += xr[c] * wr[c];
  xml[(size_t)s * COUT + o] = gb[o] - acc;
}

// K3b: transpose gw -> gwT[k][cout] (128 KB), in the dead xm ws region.
__global__ void k_gwT(const float* __restrict__ gw, float* __restrict__ gwT) {
  int i = blockIdx.x * blockDim.x + threadIdx.x;  // 32768
  int k = i >> 8, c = i & 255;
  gwT[(size_t)k * COUT + c] = gw[(size_t)c * CIN + k];
}

// K4 v7: out = PReLU(LN(x@gwT + xml[batch]))
// = v6 with ONE change: inner accumulation written as explicit fmaf chains
// (4 v_fmac per 4 MACs). v6's `acc += a*b + c*d + ...` compiled to
// mul+3fma+add = 5 VALU per 4 MACs -- that 25% instr overhead fully
// explains the 53 TF @ 76% VALUBusy (R14 counters). Same math, only
// reassociated; 64 independent 4-deep chains per kc.
__global__ __launch_bounds__(256, 2) void k_main_v7(
    const float* __restrict__ x, const int* __restrict__ batch,
    const float* __restrict__ gwT, const float* __restrict__ xml,
    const float* __restrict__ lnw, const float* __restrict__ lnb,
    const float* __restrict__ prelu, float* __restrict__ out, int N) {
  __shared__ float xs[BM * XLD];  // 33,792 B : x rows, all 128 k

  const int tid = threadIdx.x;
  const int ty = tid >> 6;        // wave id = 16-row group
  const int tx = tid & 63;
  const int c0 = tx * 4;
  const size_t row0 = (size_t)blockIdx.x * BM;

  // stage x rows: 64 rows x 32 float4 chunks = 2048, 8 per thread
#pragma unroll
  for (int i = 0; i < 8; ++i) {
    int idx = tid + i * 256;
    int r = idx >> 5, ch = idx & 31;
    size_t gr = row0 + r;
    if (gr >= (size_t)N) gr = (size_t)N - 1;  // N%64==0: never fires
    *(float4*)&xs[r * XLD + ch * 4] = *(const float4*)(x + gr * CIN + ch * 4);
  }
  __syncthreads();

  float4 acc[16];
#pragma unroll
  for (int r = 0; r < 16; ++r) acc[r] = (float4){0.f, 0.f, 0.f, 0.f};

  // double-buffered weight prefetch over 32 k-chunks of 4
  const float* gk0 = gwT + c0;
  float4 w0 = *(const float4*)(gk0);
  float4 w1 = *(const float4*)(gk0 + COUT);
  float4 w2 = *(const float4*)(gk0 + 2 * COUT);
  float4 w3 = *(const float4*)(gk0 + 3 * COUT);
  for (int kc = 0; kc < 32; ++kc) {
    int kn = (kc < 31) ? (kc + 1) : 31;
    const float* gk = gwT + (size_t)(kn * 4) * COUT + c0;
    float4 n0 = *(const float4*)(gk);
    float4 n1 = *(const float4*)(gk + COUT);
    float4 n2 = *(const float4*)(gk + 2 * COUT);
    float4 n3 = *(const float4*)(gk + 3 * COUT);
#pragma unroll
    for (int r = 0; r < 16; ++r) {
      float4 xv = *(const float4*)&xs[(ty * 16 + r) * XLD + kc * 4];  // broadcast
      acc[r].x = fmaf(xv.x, w0.x, acc[r].x);
      acc[r].y = fmaf(xv.x, w0.y, acc[r].y);
      acc[r].z = fmaf(xv.x, w0.z, acc[r].z);
      acc[r].w = fmaf(xv.x, w0.w, acc[r].w);
      acc[r].x = fmaf(xv.y, w1.x, acc[r].x);
      acc[r].y = fmaf(xv.y, w1.y, acc[r].y);
      acc[r].z = fmaf(xv.y, w1.z, acc[r].z);
      acc[r].w = fmaf(xv.y, w1.w, acc[r].w);
      acc[r].x = fmaf(xv.z, w2.x, acc[r].x);
      acc[r].y = fmaf(xv.z, w2.y, acc[r].y);
      acc[r].z = fmaf(xv.z, w2.z, acc[r].z);
      acc[r].w = fmaf(xv.z, w2.w, acc[r].w);
      acc[r].x = fmaf(xv.w, w3.x, acc[r].x);
      acc[r].y = fmaf(xv.w, w3.y, acc[r].y);
      acc[r].z = fmaf(xv.w, w3.z, acc[r].z);
      acc[r].w = fmaf(xv.w, w3.w, acc[r].w);
    }
    w0 = n0; w1 = n1; w2 = n2; w3 = n3;
  }

  // epilogue: whole wave handles one row at a time -> 64-lane LN reduce
  const float4 lw4 = *(const float4*)(lnw + c0);
  const float4 lb4 = *(const float4*)(lnb + c0);
  const float asl = prelu[0];
#pragma unroll
  for (int r = 0; r < 16; ++r) {
    size_t row = row0 + (size_t)(ty * 16 + r);
    if (row >= (size_t)N) continue;         // wave-uniform
    const float* xmlr = xml + (size_t)batch[row] * COUT;
    float4 m4 = *(const float4*)(xmlr + c0);
    float4 v;
    v.x = acc[r].x + m4.x; v.y = acc[r].y + m4.y;
    v.z = acc[r].z + m4.z; v.w = acc[r].w + m4.w;
    float sum = v.x + v.y + v.z + v.w;
    float ssq = v.x * v.x + v.y * v.y + v.z * v.z + v.w * v.w;
#pragma unroll
    for (int m = 1; m < 64; m <<= 1) {      // full-wave reduce over 256 cols
      sum += __shfl_xor(sum, m);
      ssq += __shfl_xor(ssq, m);
    }
    float mu = sum * (1.f / 256.f);
    float var = ssq * (1.f / 256.f) - mu * mu;
    float rs = rsqrtf(var + LN_EPS);
    float4 o; float t;
    t = (v.x - mu) * rs * lw4.x + lb4.x; o.x = (t >= 0.f) ? t : asl * t;
    t = (v.y - mu) * rs * lw4.y + lb4.y; o.y = (t >= 0.f) ? t : asl * t;
    t = (v.z - mu) * rs * lw4.z + lb4.z; o.z = (t >= 0.f) ? t : asl * t;
    t = (v.w - mu) * rs * lw4.w + lb4.w; o.w = (t >= 0.f) ? t : asl * t;
    *(float4*)(out + row * COUT + c0) = o;
  }
}

extern "C" void kernel_launch(void* const* d_in, const int* in_sizes, int n_in,
                              void* d_out, int out_size, void* d_ws, size_t ws_size,
                              hipStream_t stream) {
  const float* x     = (const float*)d_in[0];
  const int*   batch = (const int*)d_in[1];
  const float* gw    = (const float*)d_in[2];
  const float* gb    = (const float*)d_in[3];
  const float* lw    = (const float*)d_in[4];
  const float* lnw   = (const float*)d_in[5];
  const float* lnb   = (const float*)d_in[6];
  const float* pa    = (const float*)d_in[7];
  float* out = (float*)d_out;
  const int N = in_sizes[0] / CIN;

  // ws, TOTAL 12 MB (verified): [0,4MB) enc/xm, gwT reuses it after k_lambda;
  // [4MB,12MB) xml.
  char* w8 = (char*)d_ws;
  uint_t* enc = (uint_t*)w8;
  float* xm   = (float*)w8;                  // alias of enc (in-place decode)
  float* gwT  = (float*)w8;                  // alias of xm, valid AFTER k_lambda
  float* xml  = (float*)(w8 + 4194304);

  k_xm_init<<<(S_SEG * CIN) / 256, 256, 0, stream>>>(enc);
  k_xm_scatter<<<(N + 31) / 32, CIN, 0, stream>>>(x, batch, enc, N);
  k_xm_decode<<<(S_SEG * CIN) / 256, 256, 0, stream>>>(enc, xm);
  k_lambda_f32<<<S_SEG, COUT, 0, stream>>>(xm, lw, gb, xml);
  k_gwT<<<(COUT * CIN) / 256, 256, 0, stream>>>(gw, gwT);  // xm dead now
  k_main_v7<<<(N + BM - 1) / BM, 256, 0, stream>>>(x, batch, gwT, xml, lnw, lnb, pa, out, N);
}

// Round 17
// 1189.139 us; speedup vs baseline: 3.0015x; 1.0520x over previous
//
#include <hip/hip_runtime.h>
#include <stdint.h>

typedef unsigned int uint_t;

#define S_SEG 8192
#define CIN 128
#define COUT 256
#define LN_EPS 1e-5f
#define BM 64    // rows per block (16 per wave; 8 per 32-lane half)
#define XLD 132  // padded LDS leading dim for x rows (floats)

// order-preserving f32 <-> u32 keys for atomicMax-based float max
__device__ __forceinline__ uint_t fkey(float f) {
  uint_t b = __float_as_uint(f);
  return (b & 0x80000000u) ? ~b : (b | 0x80000000u);
}
__device__ __forceinline__ float funkey(uint_t k) {
  uint_t b = (k & 0x80000000u) ? (k ^ 0x80000000u) : ~k;
  return __uint_as_float(b);
}

// K0: init encoded-max buffer to key(-inf)   [passing, verbatim]
__global__ void k_xm_init(uint_t* __restrict__ enc) {
  enc[blockIdx.x * blockDim.x + threadIdx.x] = 0x007FFFFFu;
}

// K1: segment max via atomicMax on encoded floats   [passing, verbatim]
__global__ void k_xm_scatter(const float* __restrict__ x, const int* __restrict__ batch,
                             uint_t* __restrict__ enc, int N) {
  int r0 = blockIdx.x * 32;
  int c = threadIdx.x;  // 128 threads = channels
  int rend = r0 + 32; if (rend > N) rend = N;
  int cur = batch[r0];
  float m = -INFINITY;
  for (int r = r0; r < rend; ++r) {
    int b = batch[r];
    if (b != cur) {
      atomicMax(&enc[(size_t)cur * CIN + c], fkey(m));
      cur = b;
      m = -INFINITY;
    }
    m = fmaxf(m, x[(size_t)r * CIN + c]);
  }
  atomicMax(&enc[(size_t)cur * CIN + c], fkey(m));
}

// K2: decode in place; -inf (empty segment) -> 0   [passing, verbatim]
__global__ void k_xm_decode(uint_t* __restrict__ enc, float* __restrict__ xm) {
  int i = blockIdx.x * blockDim.x + threadIdx.x;
  float f = funkey(enc[i]);
  xm[i] = (f >= -3.0e38f && f <= 3.0e38f) ? f : 0.0f;
}

// K3: xml[s][o] = gamma_b[o] - dot(xm[s,:], lambda_w[o,:])   [passing, verbatim]
__global__ void k_lambda_f32(const float* __restrict__ xm, const float* __restrict__ lw,
                             const float* __restrict__ gb, float* __restrict__ xml) {
  int s = blockIdx.x;   // 0..8191
  int o = threadIdx.x;  // 0..255
  const float* xr = xm + (size_t)s * CIN;
  const float* wr = lw + (size_t)o * CIN;
  float acc = 0.f;
  for (int c = 0; c < CIN; ++c) acc += xr[c] * wr[c];
  xml[(size_t)s * COUT + o] = gb[o] - acc;
}

// K3b: transpose gw -> gwT[k][cout] (128 KB), in the dead xm ws region.
__global__ void k_gwT(const float* __restrict__ gw, float* __restrict__ gwT) {
  int i = blockIdx.x * blockDim.x + threadIdx.x;  // 32768
  int k = i >> 8, c = i & 255;
  gwT[(size_t)k * COUT + c] = gw[(size_t)c * CIN + k];
}

// --- v8 weight-buffer macros. Suffixes start with a LETTER (a0..b3) so the
// token paste P##a0 forms a valid identifier (R16 lesson: P##0a dies because
// `0a.x` lexes as one pp-number token).
#define WDECL(P) float4 P##a0, P##a1, P##a2, P##a3, P##b0, P##b1, P##b2, P##b3
#define WLOAD(P, kk) do {                                                     \
    const float* g_ = gwT + (size_t)((kk) * 4) * COUT + c0;                   \
    P##a0 = *(const float4*)(g_);           P##b0 = *(const float4*)(g_ + 4); \
    P##a1 = *(const float4*)(g_ + COUT);    P##b1 = *(const float4*)(g_ + COUT + 4); \
    P##a2 = *(const float4*)(g_ + 2*COUT);  P##b2 = *(const float4*)(g_ + 2*COUT + 4); \
    P##a3 = *(const float4*)(g_ + 3*COUT);  P##b3 = *(const float4*)(g_ + 3*COUT + 4); \
  } while (0)
#define WBURST(P, kk) do {                                                    \
    _Pragma("unroll")                                                         \
    for (int r = 0; r < 8; ++r) {                                             \
      float4 xv = *(const float4*)&xsrow[r * XLD + (kk) * 4];                 \
      accA[r].x = fmaf(xv.x, P##a0.x, accA[r].x);                             \
      accA[r].y = fmaf(xv.x, P##a0.y, accA[r].y);                             \
      accA[r].z = fmaf(xv.x, P##a0.z, accA[r].z);                             \
      accA[r].w = fmaf(xv.x, P##a0.w, accA[r].w);                             \
      accB[r].x = fmaf(xv.x, P##b0.x, accB[r].x);                             \
      accB[r].y = fmaf(xv.x, P##b0.y, accB[r].y);                             \
      accB[r].z = fmaf(xv.x, P##b0.z, accB[r].z);                             \
      accB[r].w = fmaf(xv.x, P##b0.w, accB[r].w);                             \
      accA[r].x = fmaf(xv.y, P##a1.x, accA[r].x);                             \
      accA[r].y = fmaf(xv.y, P##a1.y, accA[r].y);                             \
      accA[r].z = fmaf(xv.y, P##a1.z, accA[r].z);                             \
      accA[r].w = fmaf(xv.y, P##a1.w, accA[r].w);                             \
      accB[r].x = fmaf(xv.y, P##b1.x, accB[r].x);                             \
      accB[r].y = fmaf(xv.y, P##b1.y, accB[r].y);                             \
      accB[r].z = fmaf(xv.y, P##b1.z, accB[r].z);                             \
      accB[r].w = fmaf(xv.y, P##b1.w, accB[r].w);                             \
      accA[r].x = fmaf(xv.z, P##a2.x, accA[r].x);                             \
      accA[r].y = fmaf(xv.z, P##a2.y, accA[r].y);                             \
      accA[r].z = fmaf(xv.z, P##a2.z, accA[r].z);                             \
      accA[r].w = fmaf(xv.z, P##a2.w, accA[r].w);                             \
      accB[r].x = fmaf(xv.z, P##b2.x, accB[r].x);                             \
      accB[r].y = fmaf(xv.z, P##b2.y, accB[r].y);                             \
      accB[r].z = fmaf(xv.z, P##b2.z, accB[r].z);                             \
      accB[r].w = fmaf(xv.z, P##b2.w, accB[r].w);                             \
      accA[r].x = fmaf(xv.w, P##a3.x, accA[r].x);                             \
      accA[r].y = fmaf(xv.w, P##a3.y, accA[r].y);                             \
      accA[r].z = fmaf(xv.w, P##a3.z, accA[r].z);                             \
      accA[r].w = fmaf(xv.w, P##a3.w, accA[r].w);                             \
      accB[r].x = fmaf(xv.w, P##b3.x, accB[r].x);                             \
      accB[r].y = fmaf(xv.w, P##b3.y, accB[r].y);                             \
      accB[r].z = fmaf(xv.w, P##b3.z, accB[r].z);                             \
      accB[r].w = fmaf(xv.w, P##b3.w, accB[r].w);                             \
    }                                                                         \
  } while (0)

// K4 v8: out = PReLU(LN(x@gwT + xml[batch]))
// Lane owns 8 cols (c0=(l&31)*8); 32-lane half-wave owns 8 rows (rh=l>>5).
// Per 16B x-read: 32 FMAs (2x v7) -> ds_reads halve. kc unrolled x2 with
// two named weight buffer sets -> zero prefetch movs.
__global__ __launch_bounds__(256, 2) void k_main_v8(
    const float* __restrict__ x, const int* __restrict__ batch,
    const float* __restrict__ gwT, const float* __restrict__ xml,
    const float* __restrict__ lnw, const float* __restrict__ lnb,
    const float* __restrict__ prelu, float* __restrict__ out, int N) {
  __shared__ float xs[BM * XLD];  // 33,792 B : x rows, all 128 k

  const int tid = threadIdx.x;
  const int ty = tid >> 6;          // wave id
  const int l = tid & 63;
  const int rh = l >> 5;            // half-wave row-octet select
  const int c0 = (l & 31) * 8;      // 8 cols per lane
  const size_t row0 = (size_t)blockIdx.x * BM;
  const int rbase = ty * 16 + rh * 8;

  // stage x rows: 64 rows x 32 float4 chunks = 2048, 8 per thread
#pragma unroll
  for (int i = 0; i < 8; ++i) {
    int idx = tid + i * 256;
    int r = idx >> 5, ch = idx & 31;
    size_t gr = row0 + r;
    if (gr >= (size_t)N) gr = (size_t)N - 1;  // N%64==0: never fires
    *(float4*)&xs[r * XLD + ch * 4] = *(const float4*)(x + gr * CIN + ch * 4);
  }
  __syncthreads();

  const float* xsrow = &xs[rbase * XLD];
  float4 accA[8], accB[8];
#pragma unroll
  for (int r = 0; r < 8; ++r) {
    accA[r] = (float4){0.f, 0.f, 0.f, 0.f};
    accB[r] = (float4){0.f, 0.f, 0.f, 0.f};
  }

  WDECL(A); WDECL(B);
  WLOAD(A, 0);
  for (int kc = 0; kc < 32; kc += 2) {
    WLOAD(B, kc + 1);                      // kc+1 <= 31 always
    WBURST(A, kc);
    int kn = (kc + 2 < 32) ? (kc + 2) : 31;
    WLOAD(A, kn);                          // last iter: harmless re-load
    WBURST(B, kc + 1);
  }

  // epilogue: lane's row = rbase + r; LN reduce across the 32-lane half
  const float4 lwa = *(const float4*)(lnw + c0);
  const float4 lwb = *(const float4*)(lnw + c0 + 4);
  const float4 lba = *(const float4*)(lnb + c0);
  const float4 lbb = *(const float4*)(lnb + c0 + 4);
  const float asl = prelu[0];
#pragma unroll
  for (int r = 0; r < 8; ++r) {
    size_t row = row0 + (size_t)(rbase + r);
    if (row >= (size_t)N) continue;        // uniform within the half
    const float* xmlr = xml + (size_t)batch[row] * COUT;
    float4 ma = *(const float4*)(xmlr + c0);
    float4 mb = *(const float4*)(xmlr + c0 + 4);
    float4 va, vb;
    va.x = accA[r].x + ma.x; va.y = accA[r].y + ma.y;
    va.z = accA[r].z + ma.z; va.w = accA[r].w + ma.w;
    vb.x = accB[r].x + mb.x; vb.y = accB[r].y + mb.y;
    vb.z = accB[r].z + mb.z; vb.w = accB[r].w + mb.w;
    float sum = va.x + va.y + va.z + va.w + vb.x + vb.y + vb.z + vb.w;
    float ssq = va.x * va.x + va.y * va.y + va.z * va.z + va.w * va.w +
                vb.x * vb.x + vb.y * vb.y + vb.z * vb.z + vb.w * vb.w;
#pragma unroll
    for (int m = 1; m < 32; m <<= 1) {     // reduce within the 32-lane half
      sum += __shfl_xor(sum, m);
      ssq += __shfl_xor(ssq, m);
    }
    float mu = sum * (1.f / 256.f);
    float var = ssq * (1.f / 256.f) - mu * mu;
    float rs = rsqrtf(var + LN_EPS);
    float4 oa, ob; float t;
    t = (va.x - mu) * rs * lwa.x + lba.x; oa.x = (t >= 0.f) ? t : asl * t;
    t = (va.y - mu) * rs * lwa.y + lba.y; oa.y = (t >= 0.f) ? t : asl * t;
    t = (va.z - mu) * rs * lwa.z + lba.z; oa.z = (t >= 0.f) ? t : asl * t;
    t = (va.w - mu) * rs * lwa.w + lba.w; oa.w = (t >= 0.f) ? t : asl * t;
    t = (vb.x - mu) * rs * lwb.x + lbb.x; ob.x = (t >= 0.f) ? t : asl * t;
    t = (vb.y - mu) * rs * lwb.y + lbb.y; ob.y = (t >= 0.f) ? t : asl * t;
    t = (vb.z - mu) * rs * lwb.z + lbb.z; ob.z = (t >= 0.f) ? t : asl * t;
    t = (vb.w - mu) * rs * lwb.w + lbb.w; ob.w = (t >= 0.f) ? t : asl * t;
    float* orow = out + row * COUT + c0;
    *(float4*)(orow) = oa;
    *(float4*)(orow + 4) = ob;
  }
}

extern "C" void kernel_launch(void* const* d_in, const int* in_sizes, int n_in,
                              void* d_out, int out_size, void* d_ws, size_t ws_size,
                              hipStream_t stream) {
  const float* x     = (const float*)d_in[0];
  const int*   batch = (const int*)d_in[1];
  const float* gw    = (const float*)d_in[2];
  const float* gb    = (const float*)d_in[3];
  const float* lw    = (const float*)d_in[4];
  const float* lnw   = (const float*)d_in[5];
  const float* lnb   = (const float*)d_in[6];
  const float* pa    = (const float*)d_in[7];
  float* out = (float*)d_out;
  const int N = in_sizes[0] / CIN;

  // ws, TOTAL 12 MB (verified): [0,4MB) enc/xm, gwT reuses it after k_lambda;
  // [4MB,12MB) xml.
  char* w8 = (char*)d_ws;
  uint_t* enc = (uint_t*)w8;
  float* xm   = (float*)w8;                  // alias of enc (in-place decode)
  float* gwT  = (float*)w8;                  // alias of xm, valid AFTER k_lambda
  float* xml  = (float*)(w8 + 4194304);

  k_xm_init<<<(S_SEG * CIN) / 256, 256, 0, stream>>>(enc);
  k_xm_scatter<<<(N + 31) / 32, CIN, 0, stream>>>(x, batch, enc, N);
  k_xm_decode<<<(S_SEG * CIN) / 256, 256, 0, stream>>>(enc, xm);
  k_lambda_f32<<<S_SEG, COUT, 0, stream>>>(xm, lw, gb, xml);
  k_gwT<<<(COUT * CIN) / 256, 256, 0, stream>>>(gw, gwT);  // xm dead now
  k_main_v8<<<(N + BM - 1) / BM, 256, 0, stream>>>(x, batch, gwT, xml, lnw, lnb, pa, out, N);
}